// Round 11
// baseline (188.906 us; speedup 1.0000x reference)
//
#include <hip/hip_runtime.h>
#include <hip/hip_bf16.h>
#include <math.h>

typedef __bf16 bf16_t;
typedef bf16_t bf16x8 __attribute__((ext_vector_type(8)));
typedef bf16_t bf16x2 __attribute__((ext_vector_type(2)));
typedef float f32x2 __attribute__((ext_vector_type(2)));
typedef float f32x4 __attribute__((ext_vector_type(4)));
typedef float f32x16 __attribute__((ext_vector_type(16)));
typedef unsigned short u16;
typedef unsigned int u32;
typedef u32 u32x2 __attribute__((ext_vector_type(2)));
typedef u32 u32x4 __attribute__((ext_vector_type(4)));

#define AS1 __attribute__((address_space(1)))
#define AS3 __attribute__((address_space(3)))

#define LOG2E 1.4426950408889634f
#define THR_L2 11.541560327111707f   /* 8 * log2(e) */

static __device__ __forceinline__ void gll16(const void* g, void* l){
  __builtin_amdgcn_global_load_lds((const AS1 u32*)g, (AS3 u32*)l, 16, 0, 0);
}

static __device__ __forceinline__ u16 f2bf(float f){
  u32 u = __builtin_bit_cast(u32, f);
  u = u + 0x7FFFu + ((u >> 16) & 1u);
  return (u16)(u >> 16);
}

static __device__ __forceinline__ u32 pk2(float a, float b){
  f32x2 v = {a, b};
  bf16x2 w = __builtin_convertvector(v, bf16x2);
  return __builtin_bit_cast(u32, w);
}

static __device__ __forceinline__ float ex2(float x){
#if __has_builtin(__builtin_amdgcn_exp2f)
  return __builtin_amdgcn_exp2f(x);
#else
  return __expf(0.6931471805599453f * x);
#endif
}

// exchange halves across lane<32 / lane>=32
static __device__ __forceinline__ void swap32(u32& a, u32& b, int hi){
#if __has_builtin(__builtin_amdgcn_permlane32_swap)
  auto r = __builtin_amdgcn_permlane32_swap((int)a, (int)b, false, false);
  a = (u32)r[0];
  b = (u32)r[1];
#else
  u32 xa = (u32)__shfl_xor((int)a, 32);
  u32 xb = (u32)__shfl_xor((int)b, 32);
  u32 na = hi ? xb : a;
  u32 nb = hi ? b : xa;
  a = na; b = nb;
#endif
}

// ---------------- fused prep: W^T concat (0-191), RoPE table (192-703),
// mask*log2e prescale (704-735), hidden fp32->bf16 cast (736-2783) ----------------
__global__ __launch_bounds__(256) void k_prep(const float* __restrict__ h, u16* __restrict__ hb,
                        float* __restrict__ cs, const float* __restrict__ mask,
                        float* __restrict__ mkl,
                        const float* __restrict__ Wq, const float* __restrict__ Wk,
                        const float* __restrict__ Wv, const float* __restrict__ bq,
                        const float* __restrict__ bk, const float* __restrict__ bv,
                        u16* __restrict__ wt, float* __restrict__ bc){
  __shared__ float T[64][65];
  int blk = blockIdx.x;
  int tid = threadIdx.x;

  if (blk < 192){
    // ---- W^T concat via LDS tiles ----
    int t = blk >> 6, rem = blk & 63;
    int tj = rem >> 3, tk = rem & 7;
    int j0 = tj * 64, k0 = tk * 64;
    const float* W = (t == 0) ? Wq : (t == 1 ? Wk : Wv);

#pragma unroll
    for (int it = 0; it < 4; ++it){
      int idx = it * 256 + tid;
      int r = idx >> 4, c4 = idx & 15;
      float4 v = *(const float4*)&W[(size_t)(k0 + r) * 512 + j0 + c4 * 4];
      T[r][c4 * 4 + 0] = v.x; T[r][c4 * 4 + 1] = v.y;
      T[r][c4 * 4 + 2] = v.z; T[r][c4 * 4 + 3] = v.w;
    }
    __syncthreads();

#pragma unroll
    for (int it = 0; it < 2; ++it){
      int idx = it * 256 + tid;
      int rr = idx >> 3, g8 = idx & 7;
      u32x4 wv;
#pragma unroll
      for (int e = 0; e < 4; ++e)
        wv[e] = pk2(T[g8 * 8 + 2 * e][rr], T[g8 * 8 + 2 * e + 1][rr]);
      *(u32x4*)&wt[(size_t)(t * 512 + j0 + rr) * 512 + k0 + g8 * 8] = wv;
    }

    int gi = blk * 256 + tid;
    if (gi < 1536){
      int tt = gi >> 9, jj = gi & 511;
      const float* bsrc = (tt == 0) ? bq : (tt == 1 ? bk : bv);
      bc[gi] = bsrc[jj];
    }
  } else if (blk < 704){
    // ---- RoPE {cos,sin} pair table [4096][64] ----
    int idx = (blk - 192) * 256 + tid;          // 4096 * 32
    int s = idx >> 5, i = idx & 31;
    double invf = 1.0 / pow(10000.0, (double)(2 * i) / 64.0);
    float ang = (float)s * (float)invf;
    float sn, cv;
    sincosf(ang, &sn, &cv);
    f32x4 v = {cv, sn, cv, sn};
    *(f32x4*)&cs[(size_t)s * 128 + i * 4] = v;
  } else if (blk < 736){
    // ---- mask * log2e prescale (2 x 4096) ----
    int idx = (blk - 704) * 256 + tid;
    mkl[idx] = mask[idx] * LOG2E;
  } else {
    // ---- hidden fp32 -> bf16 cast ----
    const int n4 = (2 * 4096 * 512) / 4;
    int i = (blk - 736) * 256 + tid;
    int stride = (gridDim.x - 736) * 256;
    for (; i < n4; i += stride){
      float4 v = ((const float4*)h)[i];
      ushort4 o;
      o.x = f2bf(v.x); o.y = f2bf(v.y); o.z = f2bf(v.z); o.w = f2bf(v.w);
      ((ushort4*)hb)[i] = o;
    }
  }
}

// ---------------- fused QKV GEMM + bias + RoPE + layout ----------------
// q pre-scaled by 0.125*log2e (log2-domain scores downstream)
__global__ __launch_bounds__(256) void k_proj(const u16* __restrict__ hb, const u16* __restrict__ wt,
                      const float* __restrict__ bc, const float* __restrict__ cs,
                      u16* __restrict__ qws, u16* __restrict__ kws, u16* __restrict__ vt){
  __shared__ __align__(16) u16 SH[2][128 * 64];
  u16* At = SH[0];
  u16* Bt = SH[1];
  int tid = threadIdx.x;
  int lane = tid & 63;
  int c = lane & 15, g = lane >> 4;
  int wave = tid >> 6;
  int wm = wave >> 1, wn = wave & 1;
  int m0 = blockIdx.x * 128;
  int n0 = blockIdx.y * 128;

  const f32x4 vzero = {0.f, 0.f, 0.f, 0.f};
  f32x4 acc[4][4];
#pragma unroll
  for (int a = 0; a < 4; ++a)
#pragma unroll
    for (int b2 = 0; b2 < 4; ++b2) acc[a][b2] = vzero;

  for (int kc = 0; kc < 512; kc += 64){
    __syncthreads();
#pragma unroll
    for (int it = 0; it < 4; ++it){
      int j16 = it * 256 + tid;
      int row = j16 >> 3, u = j16 & 7;
      int us = u ^ (row & 7);
      gll16(hb + (size_t)(m0 + row) * 512 + kc + us * 8, &At[j16 * 8]);
      gll16(wt + (size_t)(n0 + row) * 512 + kc + us * 8, &Bt[j16 * 8]);
    }
    __syncthreads();
#pragma unroll
    for (int ch = 0; ch < 2; ++ch){
      bf16x8 af[4], bfg[4];
#pragma unroll
      for (int mt = 0; mt < 4; ++mt){
        int r = wm * 64 + mt * 16 + c;
        af[mt] = *(const bf16x8*)&At[r * 64 + ((g + 4 * ch) ^ (r & 7)) * 8];
      }
#pragma unroll
      for (int nt = 0; nt < 4; ++nt){
        int r = wn * 64 + nt * 16 + c;
        bfg[nt] = *(const bf16x8*)&Bt[r * 64 + ((g + 4 * ch) ^ (r & 7)) * 8];
      }
#pragma unroll
      for (int mt = 0; mt < 4; ++mt)
#pragma unroll
        for (int nt = 0; nt < 4; ++nt)
          acc[mt][nt] = __builtin_amdgcn_mfma_f32_16x16x32_bf16(af[mt], bfg[nt], acc[mt][nt], 0, 0, 0);
    }
  }

  int colbase = n0 + wn * 64;
  int typ = colbase >> 9;                     // 0=q 1=k 2=v (block-uniform)
  int head = (colbase >> 6) & 7;
  int rowbase = m0 + wm * 64;
  int bb = rowbase >> 12, s0 = rowbase & 4095;
  float bias[4];
#pragma unroll
  for (int nt = 0; nt < 4; ++nt) bias[nt] = bc[colbase + nt * 16 + c];

  if (typ == 2){
    __syncthreads();
    u16* Tw = &SH[0][0] + wave * 4096;
#pragma unroll
    for (int nt = 0; nt < 4; ++nt){
      int n = nt * 16 + c;
#pragma unroll
      for (int mt = 0; mt < 4; ++mt){
        float a0 = acc[mt][nt][0] + bias[nt];
        float a1 = acc[mt][nt][1] + bias[nt];
        float a2 = acc[mt][nt][2] + bias[nt];
        float a3 = acc[mt][nt][3] + bias[nt];
        int p = (mt * 4 + g) ^ (c & 14);
        u32x2 wv = { pk2(a0, a1), pk2(a2, a3) };
        *(u32x2*)&Tw[n * 64 + p * 4] = wv;
      }
    }
    __syncthreads();
    size_t vbase = (size_t)(bb * 8 + head) * 64 * 4096;
#pragma unroll
    for (int pass = 0; pass < 8; ++pass){
      int n = pass * 8 + (lane >> 3);
      int lu = (lane & 7) * 2;
      int p = lu ^ (n & 14);
      u32x4 vv = *(const u32x4*)&Tw[n * 64 + p * 4];
      *(u32x4*)&vt[vbase + (size_t)n * 4096 + s0 + (lane & 7) * 8] = vv;
    }
  } else {
    u16* dst = (typ == 0) ? qws : kws;
    float scale = (typ == 0) ? 0.125f * LOG2E : 1.0f;  // q carries 1/sqrt(64)*log2e
#pragma unroll
    for (int mt = 0; mt < 4; ++mt){
#pragma unroll
      for (int reg = 0; reg < 4; ++reg){
        int m = rowbase + mt * 16 + g * 4 + reg;
        int b = m >> 12, s = m & 4095;
        const f32x2* cs_s = (const f32x2*)(cs + (size_t)s * 128);
        size_t base = ((size_t)(b * 8 + head) * 4096 + s) * 64;
#pragma unroll
        for (int nt = 0; nt < 4; ++nt){
          int nn = nt * 16 + c;
          float y = acc[mt][nt][reg] + bias[nt];
          f32x2 p2 = cs_s[nn];
          float rot;
          if (nn < 32){
            rot = -(acc[mt][nt + 2][reg] + bias[nt + 2]);
          } else {
            rot = acc[mt][nt - 2][reg] + bias[nt - 2];
          }
          float o = (y * p2[0] + rot * p2[1]) * scale;
          dst[base + nn] = f2bf(o);
        }
      }
    }
  }
}

// ---------------- flash attention: 4 waves x 64q, 32x32x16 MFMA ----------------
// Absolute log2-domain scores: C-init = mkl loads (zero VALU, no -ml fold -> no
// cancellation), per-h per-lane ml init 0 (R9-proven), fast path p = ex2(sv)
// (single op/score). l via ones-MFMA. 64q needs ~190-216 regs -> lb(256,2);
// do NOT cap at 4 waves (R8: spill, 3.9GB scratch).
template<int NSPLIT>
__global__ __launch_bounds__(256, 2) void k_attn(const u16* __restrict__ qws, const u16* __restrict__ kws,
                      const u16* __restrict__ vtws, const float* __restrict__ mkl,
                      float* __restrict__ out, float* __restrict__ pctx, float* __restrict__ pml){
  __shared__ __align__(16) u16 smem[2][2][64 * 64];

  int tid = threadIdx.x;
  int lane = tid & 63;
  int q = lane & 31, hi = lane >> 5;
  int wave = tid >> 6;

  // XCD-aware bijective swizzle (grid = 256*NSPLIT, multiple of 8)
  int cpx = (gridDim.x >> 3);
  int nbid = (blockIdx.x & 7) * cpx + (blockIdx.x >> 3);
  int slice = nbid / (16 * NSPLIT);
  int rem = nbid - slice * 16 * NSPLIT;
  int ksplit = rem >> 4;                       // 0..NSPLIT-1
  int qt = rem & 15;
  int b = slice >> 3, head = slice & 7;
  int q0 = qt * 256 + wave * 64;               // 64 q per wave
  const int NT = 64 / NSPLIT;
  int kstart = ksplit * (4096 / NSPLIT);

  const u16* qs = qws + (size_t)slice * 4096 * 64;
  const u16* ks = kws + (size_t)slice * 4096 * 64;
  const u16* vs = vtws + (size_t)slice * 64 * 4096;
  const float* mk = mkl + b * 4096;            // mask * log2e

  // Q fragments for both q-halves: lane holds Q[q0 + h*32 + q][d]
  bf16x8 qf[2][4];
#pragma unroll
  for (int h = 0; h < 2; ++h){
    const u16* qrow = qs + (size_t)(q0 + h * 32 + q) * 64;
#pragma unroll
    for (int dblk = 0; dblk < 4; ++dblk)
      qf[h][dblk] = *(const bf16x8*)&qrow[dblk * 16 + hi * 8];
  }

  // ones A-fragment for the l-sum MFMA
  const u32x4 onesu = {0x3F803F80u, 0x3F803F80u, 0x3F803F80u, 0x3F803F80u};
  const bf16x8 onesf = __builtin_bit_cast(bf16x8, onesu);

  const f32x16 vz = {0.f,0.f,0.f,0.f,0.f,0.f,0.f,0.f,0.f,0.f,0.f,0.f,0.f,0.f,0.f,0.f};
  f32x16 ctx[2][2];                            // [h][dv-half]
#pragma unroll
  for (int h = 0; h < 2; ++h){ ctx[h][0] = vz; ctx[h][1] = vz; }
  f32x16 lacc[2];                              // l accumulated by MFMA; only reg[0] used
  lacc[0] = vz; lacc[1] = vz;
  float ml[2] = {0.f, 0.f};                    // per-lane running max offset, log2 domain, >= 0

  auto stage = [&](int buf, int kc){
#pragma unroll
    for (int it = 0; it < 2; ++it){
      int j = it * 256 + tid;
      int row = j >> 3, u = j & 7;
      int us = u ^ (row & 7);
      gll16(ks + (size_t)(kc + row) * 64 + us * 8, &smem[buf][0][j * 8]);
      gll16(vs + (size_t)row * 4096 + kc + us * 8, &smem[buf][1][j * 8]);
    }
  };

  stage(0, kstart);

  for (int t = 0; t < NT; ++t){
    int kc = kstart + t * 64;
    __syncthreads();
    if (t < NT - 1) stage((t + 1) & 1, kc + 64);
    const u16* Kb  = &smem[t & 1][0][0];
    const u16* Vtc = &smem[t & 1][1][0];

    // C-init = mask*log2e, pure loads (key = (r&3)+8*(r>>2)+4*hi)
    f32x16 mv[2];
#pragma unroll
    for (int kb = 0; kb < 2; ++kb)
#pragma unroll
      for (int gg = 0; gg < 4; ++gg){
        float4 m4 = *(const float4*)&mk[kc + kb * 32 + gg * 8 + hi * 4];
        mv[kb][4 * gg + 0] = m4.x; mv[kb][4 * gg + 1] = m4.y;
        mv[kb][4 * gg + 2] = m4.z; mv[kb][4 * gg + 3] = m4.w;
      }

    // QK^T (swapped): S^T[key][q] in absolute log2 domain; kf shared by both halves
    f32x16 sv[2][2];                            // [h][kb]
    __builtin_amdgcn_s_setprio(1);
#pragma unroll
    for (int kb = 0; kb < 2; ++kb){
      f32x16 a0 = mv[kb], a1 = mv[kb];
#pragma unroll
      for (int dblk = 0; dblk < 4; ++dblk){
        int row = kb * 32 + q;
        bf16x8 kf = *(const bf16x8*)&Kb[row * 64 + (((dblk * 2 + hi) ^ (row & 7)) * 8)];
        a0 = __builtin_amdgcn_mfma_f32_32x32x16_bf16(kf, qf[0][dblk], a0, 0, 0, 0);
        a1 = __builtin_amdgcn_mfma_f32_32x32x16_bf16(kf, qf[1][dblk], a1, 0, 0, 0);
      }
      sv[0][kb] = a0;
      sv[1][kb] = a1;
    }
    __builtin_amdgcn_s_setprio(0);

#pragma unroll
    for (int h = 0; h < 2; ++h){
      // tile max: max3-shaped triple tree over 32 values
#define SVV(j) sv[h][(j) >> 4][(j) & 15]
      float tr[11];
#pragma unroll
      for (int i = 0; i < 10; ++i)
        tr[i] = fmaxf(fmaxf(SVV(3 * i), SVV(3 * i + 1)), SVV(3 * i + 2));
      tr[10] = fmaxf(SVV(30), SVV(31));
#undef SVV
      float u0 = fmaxf(fmaxf(tr[0], tr[1]), tr[2]);
      float u1 = fmaxf(fmaxf(tr[3], tr[4]), tr[5]);
      float u2 = fmaxf(fmaxf(tr[6], tr[7]), tr[8]);
      float u3 = fmaxf(tr[9], tr[10]);
      float pmax = fmaxf(fmaxf(fmaxf(u0, u1), u2), u3);
      pmax = fmaxf(pmax, __shfl_xor(pmax, 32));

      // defer-max (T13): rescale only when headroom exceeded
      if (__any(pmax - ml[h] > THR_L2)){
        float delta = fmaxf(pmax - ml[h], 0.f);
        ml[h] += delta;
        float al = ex2(-delta);
        lacc[h][0] *= al;
#pragma unroll
        for (int r = 0; r < 16; ++r){ ctx[h][0][r] *= al; ctx[h][1][r] *= al; }
      }
    }

    // p = exp2(sv [- ml]); fast path (ml==0 everywhere) is 1 op/score
    if (__all(fmaxf(ml[0], ml[1]) == 0.f)){
#pragma unroll
      for (int h = 0; h < 2; ++h)
#pragma unroll
        for (int kb = 0; kb < 2; ++kb)
#pragma unroll
          for (int r = 0; r < 16; ++r)
            sv[h][kb][r] = ex2(sv[h][kb][r]);
    } else {
#pragma unroll
      for (int h = 0; h < 2; ++h)
#pragma unroll
        for (int kb = 0; kb < 2; ++kb)
#pragma unroll
          for (int r = 0; r < 16; ++r)
            sv[h][kb][r] = ex2(sv[h][kb][r] - ml[h]);
    }

    // pack P and assemble PV B-frags per q-half
    bf16x8 pb[2][4];
#pragma unroll
    for (int h = 0; h < 2; ++h){
      u32 W0[2][4], W1[2][4];
#pragma unroll
      for (int kb = 0; kb < 2; ++kb)
#pragma unroll
        for (int g = 0; g < 4; ++g){
          W0[kb][g] = pk2(sv[h][kb][4 * g + 0], sv[h][kb][4 * g + 1]);
          W1[kb][g] = pk2(sv[h][kb][4 * g + 2], sv[h][kb][4 * g + 3]);
        }
#pragma unroll
      for (int kblk = 0; kblk < 4; ++kblk){
        int kb = kblk >> 1, j = kblk & 1;
        u32 w0 = W0[kb][2 * j + 0], w2 = W0[kb][2 * j + 1];
        u32 w1 = W1[kb][2 * j + 0], w3 = W1[kb][2 * j + 1];
        swap32(w0, w2, hi);
        swap32(w1, w3, hi);
        u32x4 wv = {w0, w1, w2, w3};
        pb[h][kblk] = __builtin_bit_cast(bf16x8, wv);
      }
    }

    // PV: O^T[dv][q] += V^T[dv][key] * P^T[key][q]; l-sum via ones-row MFMA
    __builtin_amdgcn_s_setprio(1);
#pragma unroll
    for (int kblk = 0; kblk < 4; ++kblk){
      int row0 = q;
      bf16x8 vf0 = *(const bf16x8*)&Vtc[row0 * 64 + (((kblk * 2 + hi) ^ (row0 & 7)) * 8)];
      ctx[0][0] = __builtin_amdgcn_mfma_f32_32x32x16_bf16(vf0, pb[0][kblk], ctx[0][0], 0, 0, 0);
      ctx[1][0] = __builtin_amdgcn_mfma_f32_32x32x16_bf16(vf0, pb[1][kblk], ctx[1][0], 0, 0, 0);
      int row1 = 32 + q;
      bf16x8 vf1 = *(const bf16x8*)&Vtc[row1 * 64 + (((kblk * 2 + hi) ^ (row1 & 7)) * 8)];
      ctx[0][1] = __builtin_amdgcn_mfma_f32_32x32x16_bf16(vf1, pb[0][kblk], ctx[0][1], 0, 0, 0);
      ctx[1][1] = __builtin_amdgcn_mfma_f32_32x32x16_bf16(vf1, pb[1][kblk], ctx[1][1], 0, 0, 0);
      lacc[0] = __builtin_amdgcn_mfma_f32_32x32x16_bf16(onesf, pb[0][kblk], lacc[0], 0, 0, 0);
      lacc[1] = __builtin_amdgcn_mfma_f32_32x32x16_bf16(onesf, pb[1][kblk], lacc[1], 0, 0, 0);
    }
    __builtin_amdgcn_s_setprio(0);
  }

  if (NSPLIT == 1){
#pragma unroll
    for (int h = 0; h < 2; ++h){
      float invl = 1.0f / lacc[h][0];
      float* orow = out + (size_t)(b * 4096 + q0 + h * 32 + q) * 512 + head * 64;
#pragma unroll
      for (int g = 0; g < 4; ++g){
        float4 o0, o1;
        o0.x = ctx[h][0][4 * g + 0] * invl; o0.y = ctx[h][0][4 * g + 1] * invl;
        o0.z = ctx[h][0][4 * g + 2] * invl; o0.w = ctx[h][0][4 * g + 3] * invl;
        *(float4*)&orow[8 * g + 4 * hi] = o0;
        o1.x = ctx[h][1][4 * g + 0] * invl; o1.y = ctx[h][1][4 * g + 1] * invl;
        o1.z = ctx[h][1][4 * g + 2] * invl; o1.w = ctx[h][1][4 * g + 3] * invl;
        *(float4*)&orow[32 + 8 * g + 4 * hi] = o1;
      }
    }
  } else {
#pragma unroll
    for (int h = 0; h < 2; ++h){
      size_t row = (size_t)ksplit * 65536 + slice * 4096 + q0 + h * 32 + q;
      float* prow = pctx + row * 64;
#pragma unroll
      for (int g = 0; g < 4; ++g){
        float4 o0, o1;
        o0.x = ctx[h][0][4 * g + 0]; o0.y = ctx[h][0][4 * g + 1];
        o0.z = ctx[h][0][4 * g + 2]; o0.w = ctx[h][0][4 * g + 3];
        *(float4*)&prow[8 * g + 4 * hi] = o0;
        o1.x = ctx[h][1][4 * g + 0]; o1.y = ctx[h][1][4 * g + 1];
        o1.z = ctx[h][1][4 * g + 2]; o1.w = ctx[h][1][4 * g + 3];
        *(float4*)&prow[32 + 8 * g + 4 * hi] = o1;
      }
      if (hi == 0){
        f32x2 mlv = {ml[h], lacc[h][0]};       // ml in log2 domain
        *(f32x2*)&pml[row * 2] = mlv;
      }
    }
  }
}

// ---------------- split-K merge (ml in log2 domain) ----------------
__global__ __launch_bounds__(256) void k_merge(const float* __restrict__ pctx, const float* __restrict__ pml,
                                               float* __restrict__ out){
  int idx = blockIdx.x * 256 + threadIdx.x;   // 65536 rows * 16 quads
  int row = idx >> 4, dq = (idx & 15) * 4;
  f32x2 ml0 = *(const f32x2*)&pml[(size_t)row * 2];
  f32x2 ml1 = *(const f32x2*)&pml[((size_t)65536 + row) * 2];
  float ms = fmaxf(ml0[0], ml1[0]);
  float w0 = ex2(ml0[0] - ms);
  float w1 = ex2(ml1[0] - ms);
  float rdenom = 1.0f / (w0 * ml0[1] + w1 * ml1[1]);
  float4 c0 = *(const float4*)&pctx[(size_t)row * 64 + dq];
  float4 c1 = *(const float4*)&pctx[((size_t)65536 + row) * 64 + dq];
  float4 o;
  o.x = (w0 * c0.x + w1 * c1.x) * rdenom;
  o.y = (w0 * c0.y + w1 * c1.y) * rdenom;
  o.z = (w0 * c0.z + w1 * c1.z) * rdenom;
  o.w = (w0 * c0.w + w1 * c1.w) * rdenom;
  int slice = row >> 12, s = row & 4095;
  int b = slice >> 3, head = slice & 7;
  *(float4*)&out[(size_t)(b * 4096 + s) * 512 + head * 64 + dq] = o;
}

extern "C" void kernel_launch(void* const* d_in, const int* in_sizes, int n_in,
                              void* d_out, int out_size, void* d_ws, size_t ws_size,
                              hipStream_t stream) {
  const float* hidden = (const float*)d_in[0];
  const float* mask   = (const float*)d_in[1];
  const float* Wq = (const float*)d_in[2];
  const float* bq = (const float*)d_in[3];
  const float* Wk = (const float*)d_in[4];
  const float* bk = (const float*)d_in[5];
  const float* Wv = (const float*)d_in[6];
  const float* bv = (const float*)d_in[7];
  float* out = (float*)d_out;
  char* ws = (char*)d_ws;

  u16* hb    = (u16*)(ws + 0x00000000);   // 8192x512 bf16      (8 MiB)
  u16* wt    = (u16*)(ws + 0x00900000);   // 1536x512 bf16      (1.5 MiB)
  float* bc  = (float*)(ws + 0x00B00000); // 1536 f32
  float* mkl = (float*)(ws + 0x00B08000); // 2x4096 f32 (mask*log2e)
  float* cs  = (float*)(ws + 0x00B10000); // 4096x64x2 f32      (2 MiB)
  u16* qws   = (u16*)(ws + 0x00E00000);   // 16x4096x64 bf16    (8 MiB)
  u16* kws   = (u16*)(ws + 0x01600000);   // 16x4096x64 bf16
  u16* vtws  = (u16*)(ws + 0x01E00000);   // 16x64x4096 bf16
  float* pctx= (float*)(ws + 0x02600000); // 2x16 MiB
  float* pml = (float*)(ws + 0x04600000); // 2x0.5 MiB

  bool split = ws_size >= 0x04700000ull;

  k_prep<<<dim3(2784), dim3(256), 0, stream>>>(hidden, hb, cs, mask, mkl,
                                               Wq, Wk, Wv, bq, bk, bv, wt, bc);
  k_proj<<<dim3(64, 12), dim3(256), 0, stream>>>(hb, wt, bc, cs, qws, kws, vtws);
  if (split){
    k_attn<2><<<dim3(512), dim3(256), 0, stream>>>(qws, kws, vtws, mkl, out, pctx, pml);
    k_merge<<<dim3(4096), dim3(256), 0, stream>>>(pctx, pml, out);
  } else {
    k_attn<1><<<dim3(256), dim3(256), 0, stream>>>(qws, kws, vtws, mkl, out, pctx, pml);
  }
}

// Round 12
// 146.772 us; speedup vs baseline: 1.2871x; 1.2871x over previous
//
#include <hip/hip_runtime.h>
#include <hip/hip_bf16.h>
#include <math.h>

typedef __bf16 bf16_t;
typedef bf16_t bf16x8 __attribute__((ext_vector_type(8)));
typedef bf16_t bf16x2 __attribute__((ext_vector_type(2)));
typedef float f32x2 __attribute__((ext_vector_type(2)));
typedef float f32x4 __attribute__((ext_vector_type(4)));
typedef float f32x16 __attribute__((ext_vector_type(16)));
typedef unsigned short u16;
typedef unsigned int u32;
typedef u32 u32x2 __attribute__((ext_vector_type(2)));
typedef u32 u32x4 __attribute__((ext_vector_type(4)));

#define AS1 __attribute__((address_space(1)))
#define AS3 __attribute__((address_space(3)))

#define LOG2E 1.4426950408889634f

static __device__ __forceinline__ void gll16(const void* g, void* l){
  __builtin_amdgcn_global_load_lds((const AS1 u32*)g, (AS3 u32*)l, 16, 0, 0);
}

static __device__ __forceinline__ u16 f2bf(float f){
  u32 u = __builtin_bit_cast(u32, f);
  u = u + 0x7FFFu + ((u >> 16) & 1u);
  return (u16)(u >> 16);
}

static __device__ __forceinline__ u32 pk2(float a, float b){
  f32x2 v = {a, b};
  bf16x2 w = __builtin_convertvector(v, bf16x2);
  return __builtin_bit_cast(u32, w);
}

static __device__ __forceinline__ float ex2(float x){
#if __has_builtin(__builtin_amdgcn_exp2f)
  return __builtin_amdgcn_exp2f(x);
#else
  return __expf(0.6931471805599453f * x);
#endif
}

// exchange halves across lane<32 / lane>=32
static __device__ __forceinline__ void swap32(u32& a, u32& b, int hi){
#if __has_builtin(__builtin_amdgcn_permlane32_swap)
  auto r = __builtin_amdgcn_permlane32_swap((int)a, (int)b, false, false);
  a = (u32)r[0];
  b = (u32)r[1];
#else
  u32 xa = (u32)__shfl_xor((int)a, 32);
  u32 xb = (u32)__shfl_xor((int)b, 32);
  u32 na = hi ? xb : a;
  u32 nb = hi ? b : xa;
  a = na; b = nb;
#endif
}

// ---------------- fused prep: W^T concat (blocks 0-191), RoPE table (192-703),
// ---------------- hidden fp32->bf16 cast (704-2751) ----------------
__global__ __launch_bounds__(256) void k_prep(const float* __restrict__ h, u16* __restrict__ hb,
                        float* __restrict__ cs,
                        const float* __restrict__ Wq, const float* __restrict__ Wk,
                        const float* __restrict__ Wv, const float* __restrict__ bq,
                        const float* __restrict__ bk, const float* __restrict__ bv,
                        u16* __restrict__ wt, float* __restrict__ bc){
  __shared__ float T[64][65];
  int blk = blockIdx.x;
  int tid = threadIdx.x;

  if (blk < 192){
    // ---- W^T concat via LDS tiles ----
    int t = blk >> 6, rem = blk & 63;
    int tj = rem >> 3, tk = rem & 7;
    int j0 = tj * 64, k0 = tk * 64;
    const float* W = (t == 0) ? Wq : (t == 1 ? Wk : Wv);

#pragma unroll
    for (int it = 0; it < 4; ++it){
      int idx = it * 256 + tid;
      int r = idx >> 4, c4 = idx & 15;
      float4 v = *(const float4*)&W[(size_t)(k0 + r) * 512 + j0 + c4 * 4];
      T[r][c4 * 4 + 0] = v.x; T[r][c4 * 4 + 1] = v.y;
      T[r][c4 * 4 + 2] = v.z; T[r][c4 * 4 + 3] = v.w;
    }
    __syncthreads();

#pragma unroll
    for (int it = 0; it < 2; ++it){
      int idx = it * 256 + tid;
      int rr = idx >> 3, g8 = idx & 7;
      u32x4 wv;
#pragma unroll
      for (int e = 0; e < 4; ++e)
        wv[e] = pk2(T[g8 * 8 + 2 * e][rr], T[g8 * 8 + 2 * e + 1][rr]);
      *(u32x4*)&wt[(size_t)(t * 512 + j0 + rr) * 512 + k0 + g8 * 8] = wv;
    }

    int gi = blk * 256 + tid;
    if (gi < 1536){
      int tt = gi >> 9, jj = gi & 511;
      const float* bsrc = (tt == 0) ? bq : (tt == 1 ? bk : bv);
      bc[gi] = bsrc[jj];
    }
  } else if (blk < 704){
    // ---- RoPE {cos,sin} pair table [4096][64] ----
    int idx = (blk - 192) * 256 + tid;          // 4096 * 32
    int s = idx >> 5, i = idx & 31;
    double invf = 1.0 / pow(10000.0, (double)(2 * i) / 64.0);
    float ang = (float)s * (float)invf;
    float sn, cv;
    sincosf(ang, &sn, &cv);
    f32x4 v = {cv, sn, cv, sn};
    *(f32x4*)&cs[(size_t)s * 128 + i * 4] = v;
  } else {
    // ---- hidden fp32 -> bf16 cast ----
    const int n4 = (2 * 4096 * 512) / 4;
    int i = (blk - 704) * 256 + tid;
    int stride = (gridDim.x - 704) * 256;
    for (; i < n4; i += stride){
      float4 v = ((const float4*)h)[i];
      ushort4 o;
      o.x = f2bf(v.x); o.y = f2bf(v.y); o.z = f2bf(v.z); o.w = f2bf(v.w);
      ((ushort4*)hb)[i] = o;
    }
  }
}

// ---------------- fused QKV GEMM + bias + RoPE + layout ----------------
// out: q,k as [slice][4096][64] bf16 (q pre-scaled by 0.125), v as [slice][64][4096] bf16
__global__ __launch_bounds__(256) void k_proj(const u16* __restrict__ hb, const u16* __restrict__ wt,
                      const float* __restrict__ bc, const float* __restrict__ cs,
                      u16* __restrict__ qws, u16* __restrict__ kws, u16* __restrict__ vt){
  __shared__ __align__(16) u16 SH[2][128 * 64];
  u16* At = SH[0];
  u16* Bt = SH[1];
  int tid = threadIdx.x;
  int lane = tid & 63;
  int c = lane & 15, g = lane >> 4;
  int wave = tid >> 6;
  int wm = wave >> 1, wn = wave & 1;
  int m0 = blockIdx.x * 128;
  int n0 = blockIdx.y * 128;

  const f32x4 vzero = {0.f, 0.f, 0.f, 0.f};
  f32x4 acc[4][4];
#pragma unroll
  for (int a = 0; a < 4; ++a)
#pragma unroll
    for (int b2 = 0; b2 < 4; ++b2) acc[a][b2] = vzero;

  for (int kc = 0; kc < 512; kc += 64){
    __syncthreads();
#pragma unroll
    for (int it = 0; it < 4; ++it){
      int j16 = it * 256 + tid;
      int row = j16 >> 3, u = j16 & 7;
      int us = u ^ (row & 7);
      gll16(hb + (size_t)(m0 + row) * 512 + kc + us * 8, &At[j16 * 8]);
      gll16(wt + (size_t)(n0 + row) * 512 + kc + us * 8, &Bt[j16 * 8]);
    }
    __syncthreads();
#pragma unroll
    for (int ch = 0; ch < 2; ++ch){
      bf16x8 af[4], bfg[4];
#pragma unroll
      for (int mt = 0; mt < 4; ++mt){
        int r = wm * 64 + mt * 16 + c;
        af[mt] = *(const bf16x8*)&At[r * 64 + ((g + 4 * ch) ^ (r & 7)) * 8];
      }
#pragma unroll
      for (int nt = 0; nt < 4; ++nt){
        int r = wn * 64 + nt * 16 + c;
        bfg[nt] = *(const bf16x8*)&Bt[r * 64 + ((g + 4 * ch) ^ (r & 7)) * 8];
      }
#pragma unroll
      for (int mt = 0; mt < 4; ++mt)
#pragma unroll
        for (int nt = 0; nt < 4; ++nt)
          acc[mt][nt] = __builtin_amdgcn_mfma_f32_16x16x32_bf16(af[mt], bfg[nt], acc[mt][nt], 0, 0, 0);
    }
  }

  int colbase = n0 + wn * 64;
  int typ = colbase >> 9;                     // 0=q 1=k 2=v (block-uniform)
  int head = (colbase >> 6) & 7;
  int rowbase = m0 + wm * 64;
  int bb = rowbase >> 12, s0 = rowbase & 4095;
  float bias[4];
#pragma unroll
  for (int nt = 0; nt < 4; ++nt) bias[nt] = bc[colbase + nt * 16 + c];

  if (typ == 2){
    __syncthreads();
    u16* Tw = &SH[0][0] + wave * 4096;
#pragma unroll
    for (int nt = 0; nt < 4; ++nt){
      int n = nt * 16 + c;
#pragma unroll
      for (int mt = 0; mt < 4; ++mt){
        float a0 = acc[mt][nt][0] + bias[nt];
        float a1 = acc[mt][nt][1] + bias[nt];
        float a2 = acc[mt][nt][2] + bias[nt];
        float a3 = acc[mt][nt][3] + bias[nt];
        int p = (mt * 4 + g) ^ (c & 14);
        u32x2 wv = { pk2(a0, a1), pk2(a2, a3) };
        *(u32x2*)&Tw[n * 64 + p * 4] = wv;
      }
    }
    __syncthreads();
    size_t vbase = (size_t)(bb * 8 + head) * 64 * 4096;
#pragma unroll
    for (int pass = 0; pass < 8; ++pass){
      int n = pass * 8 + (lane >> 3);
      int lu = (lane & 7) * 2;
      int p = lu ^ (n & 14);
      u32x4 vv = *(const u32x4*)&Tw[n * 64 + p * 4];
      *(u32x4*)&vt[vbase + (size_t)n * 4096 + s0 + (lane & 7) * 8] = vv;
    }
  } else {
    u16* dst = (typ == 0) ? qws : kws;
    float scale = (typ == 0) ? 0.125f : 1.0f;   // fold 1/sqrt(64) into q
#pragma unroll
    for (int mt = 0; mt < 4; ++mt){
#pragma unroll
      for (int reg = 0; reg < 4; ++reg){
        int m = rowbase + mt * 16 + g * 4 + reg;
        int b = m >> 12, s = m & 4095;
        const f32x2* cs_s = (const f32x2*)(cs + (size_t)s * 128);
        size_t base = ((size_t)(b * 8 + head) * 4096 + s) * 64;
#pragma unroll
        for (int nt = 0; nt < 4; ++nt){
          int nn = nt * 16 + c;
          float y = acc[mt][nt][reg] + bias[nt];
          f32x2 p2 = cs_s[nn];
          float rot;
          if (nn < 32){
            rot = -(acc[mt][nt + 2][reg] + bias[nt + 2]);
          } else {
            rot = acc[mt][nt - 2][reg] + bias[nt - 2];
          }
          float o = (y * p2[0] + rot * p2[1]) * scale;
          dst[base + nn] = f2bf(o);
        }
      }
    }
  }
}

// ---------------- flash attention: 4 waves x 64q, 32x32x16 MFMA (R6/R10 optimum) ----------------
// Mask folded into QK accumulator init; l computed by ones-row MFMA (matrix pipe).
// 64q/wave maximizes K/V LDS-fragment reuse (each feeds 2 MFMAs); needs ~190 regs
// -> 2 waves/SIMD (lb(256,2)). Do NOT cap at 4 waves: spills (R8: 3.9GB scratch).
// Do NOT branch the exp path: live-range growth spills (R11: +45us).
template<int NSPLIT>
__global__ __launch_bounds__(256, 2) void k_attn(const u16* __restrict__ qws, const u16* __restrict__ kws,
                      const u16* __restrict__ vtws, const float* __restrict__ mask,
                      float* __restrict__ out, float* __restrict__ pctx, float* __restrict__ pml){
  __shared__ __align__(16) u16 smem[2][2][64 * 64];

  int tid = threadIdx.x;
  int lane = tid & 63;
  int q = lane & 31, hi = lane >> 5;
  int wave = tid >> 6;

  // XCD-aware bijective swizzle (grid = 256*NSPLIT, multiple of 8)
  int cpx = (gridDim.x >> 3);
  int nbid = (blockIdx.x & 7) * cpx + (blockIdx.x >> 3);
  int slice = nbid / (16 * NSPLIT);
  int rem = nbid - slice * 16 * NSPLIT;
  int ksplit = rem >> 4;                       // 0..NSPLIT-1
  int qt = rem & 15;
  int b = slice >> 3, head = slice & 7;
  int q0 = qt * 256 + wave * 64;               // 64 q per wave
  const int NT = 64 / NSPLIT;
  int kstart = ksplit * (4096 / NSPLIT);

  const u16* qs = qws + (size_t)slice * 4096 * 64;
  const u16* ks = kws + (size_t)slice * 4096 * 64;
  const u16* vs = vtws + (size_t)slice * 64 * 4096;
  const float* mk = mask + b * 4096;

  // Q fragments for both q-halves: lane holds Q[q0 + h*32 + q][d]
  bf16x8 qf[2][4];
#pragma unroll
  for (int h = 0; h < 2; ++h){
    const u16* qrow = qs + (size_t)(q0 + h * 32 + q) * 64;
#pragma unroll
    for (int dblk = 0; dblk < 4; ++dblk)
      qf[h][dblk] = *(const bf16x8*)&qrow[dblk * 16 + hi * 8];
  }

  // ones A-fragment for the l-sum MFMA
  const u32x4 onesu = {0x3F803F80u, 0x3F803F80u, 0x3F803F80u, 0x3F803F80u};
  const bf16x8 onesf = __builtin_bit_cast(bf16x8, onesu);

  const f32x16 vz = {0.f,0.f,0.f,0.f,0.f,0.f,0.f,0.f,0.f,0.f,0.f,0.f,0.f,0.f,0.f,0.f};
  f32x16 ctx[2][2];                            // [h][dv-half]
#pragma unroll
  for (int h = 0; h < 2; ++h){ ctx[h][0] = vz; ctx[h][1] = vz; }
  f32x16 lacc[2];                              // l accumulated by MFMA; only reg[0] used
  lacc[0] = vz; lacc[1] = vz;
  float m_run[2] = {-1e30f, -1e30f};
  float ml[2] = {-1e30f * LOG2E, -1e30f * LOG2E};

  auto stage = [&](int buf, int kc){
#pragma unroll
    for (int it = 0; it < 2; ++it){
      int j = it * 256 + tid;
      int row = j >> 3, u = j & 7;
      int us = u ^ (row & 7);
      gll16(ks + (size_t)(kc + row) * 64 + us * 8, &smem[buf][0][j * 8]);
      gll16(vs + (size_t)row * 4096 + kc + us * 8, &smem[buf][1][j * 8]);
    }
  };

  stage(0, kstart);

  for (int t = 0; t < NT; ++t){
    int kc = kstart + t * 64;
    __syncthreads();
    if (t < NT - 1) stage((t + 1) & 1, kc + 64);
    const u16* Kb  = &smem[t & 1][0][0];
    const u16* Vtc = &smem[t & 1][1][0];

    // mask loads -> QK accumulator init (C/D layout key = (r&3)+8*(r>>2)+4*hi)
    f32x16 mv[2];
#pragma unroll
    for (int kb = 0; kb < 2; ++kb)
#pragma unroll
      for (int gg = 0; gg < 4; ++gg){
        float4 m4 = *(const float4*)&mk[kc + kb * 32 + gg * 8 + hi * 4];
        mv[kb][4 * gg + 0] = m4.x; mv[kb][4 * gg + 1] = m4.y;
        mv[kb][4 * gg + 2] = m4.z; mv[kb][4 * gg + 3] = m4.w;
      }

    // QK^T (swapped): S^T[key][q] + mask, kf shared by both q-halves
    f32x16 sv[2][2];                            // [h][kb]
    __builtin_amdgcn_s_setprio(1);
#pragma unroll
    for (int kb = 0; kb < 2; ++kb){
      f32x16 a0 = mv[kb], a1 = mv[kb];
#pragma unroll
      for (int dblk = 0; dblk < 4; ++dblk){
        int row = kb * 32 + q;
        bf16x8 kf = *(const bf16x8*)&Kb[row * 64 + (((dblk * 2 + hi) ^ (row & 7)) * 8)];
        a0 = __builtin_amdgcn_mfma_f32_32x32x16_bf16(kf, qf[0][dblk], a0, 0, 0, 0);
        a1 = __builtin_amdgcn_mfma_f32_32x32x16_bf16(kf, qf[1][dblk], a1, 0, 0, 0);
      }
      sv[0][kb] = a0;
      sv[1][kb] = a1;
    }
    __builtin_amdgcn_s_setprio(0);

#pragma unroll
    for (int h = 0; h < 2; ++h){
      // tile max: max3-shaped triple tree over 32 values
#define SVV(j) sv[h][(j) >> 4][(j) & 15]
      float tr[11];
#pragma unroll
      for (int i = 0; i < 10; ++i)
        tr[i] = fmaxf(fmaxf(SVV(3 * i), SVV(3 * i + 1)), SVV(3 * i + 2));
      tr[10] = fmaxf(SVV(30), SVV(31));
#undef SVV
      float u0 = fmaxf(fmaxf(tr[0], tr[1]), tr[2]);
      float u1 = fmaxf(fmaxf(tr[3], tr[4]), tr[5]);
      float u2 = fmaxf(fmaxf(tr[6], tr[7]), tr[8]);
      float u3 = fmaxf(tr[9], tr[10]);
      float pmax = fmaxf(fmaxf(fmaxf(u0, u1), u2), u3);
      pmax = fmaxf(pmax, __shfl_xor(pmax, 32));

      // defer-max (T13)
      if (__any(pmax > m_run[h] + 8.f)){
        float mnew = fmaxf(m_run[h], pmax);
        float al = ex2((m_run[h] - mnew) * LOG2E);
        m_run[h] = mnew;
        ml[h] = mnew * LOG2E;
        lacc[h][0] *= al;
#pragma unroll
        for (int r = 0; r < 16; ++r){ ctx[h][0][r] *= al; ctx[h][1][r] *= al; }
      }

      // p = exp2(s*log2e - ml); sum comes from the ones-MFMA below
#pragma unroll
      for (int kb = 0; kb < 2; ++kb)
#pragma unroll
        for (int r = 0; r < 16; ++r)
          sv[h][kb][r] = ex2(fmaf(sv[h][kb][r], LOG2E, -ml[h]));
    }

    // pack P and assemble PV B-frags per q-half
    bf16x8 pb[2][4];
#pragma unroll
    for (int h = 0; h < 2; ++h){
      u32 W0[2][4], W1[2][4];
#pragma unroll
      for (int kb = 0; kb < 2; ++kb)
#pragma unroll
        for (int g = 0; g < 4; ++g){
          W0[kb][g] = pk2(sv[h][kb][4 * g + 0], sv[h][kb][4 * g + 1]);
          W1[kb][g] = pk2(sv[h][kb][4 * g + 2], sv[h][kb][4 * g + 3]);
        }
#pragma unroll
      for (int kblk = 0; kblk < 4; ++kblk){
        int kb = kblk >> 1, j = kblk & 1;
        u32 w0 = W0[kb][2 * j + 0], w2 = W0[kb][2 * j + 1];
        u32 w1 = W1[kb][2 * j + 0], w3 = W1[kb][2 * j + 1];
        swap32(w0, w2, hi);
        swap32(w1, w3, hi);
        u32x4 wv = {w0, w1, w2, w3};
        pb[h][kblk] = __builtin_bit_cast(bf16x8, wv);
      }
    }

    // PV: O^T[dv][q] += V^T[dv][key] * P^T[key][q]; plus l-sum via ones-row MFMA
    __builtin_amdgcn_s_setprio(1);
#pragma unroll
    for (int kblk = 0; kblk < 4; ++kblk){
      int row0 = q;
      bf16x8 vf0 = *(const bf16x8*)&Vtc[row0 * 64 + (((kblk * 2 + hi) ^ (row0 & 7)) * 8)];
      ctx[0][0] = __builtin_amdgcn_mfma_f32_32x32x16_bf16(vf0, pb[0][kblk], ctx[0][0], 0, 0, 0);
      ctx[1][0] = __builtin_amdgcn_mfma_f32_32x32x16_bf16(vf0, pb[1][kblk], ctx[1][0], 0, 0, 0);
      int row1 = 32 + q;
      bf16x8 vf1 = *(const bf16x8*)&Vtc[row1 * 64 + (((kblk * 2 + hi) ^ (row1 & 7)) * 8)];
      ctx[0][1] = __builtin_amdgcn_mfma_f32_32x32x16_bf16(vf1, pb[0][kblk], ctx[0][1], 0, 0, 0);
      ctx[1][1] = __builtin_amdgcn_mfma_f32_32x32x16_bf16(vf1, pb[1][kblk], ctx[1][1], 0, 0, 0);
      lacc[0] = __builtin_amdgcn_mfma_f32_32x32x16_bf16(onesf, pb[0][kblk], lacc[0], 0, 0, 0);
      lacc[1] = __builtin_amdgcn_mfma_f32_32x32x16_bf16(onesf, pb[1][kblk], lacc[1], 0, 0, 0);
    }
    __builtin_amdgcn_s_setprio(0);
  }

  if (NSPLIT == 1){
#pragma unroll
    for (int h = 0; h < 2; ++h){
      float invl = 1.0f / lacc[h][0];
      float* orow = out + (size_t)(b * 4096 + q0 + h * 32 + q) * 512 + head * 64;
#pragma unroll
      for (int g = 0; g < 4; ++g){
        float4 o0, o1;
        o0.x = ctx[h][0][4 * g + 0] * invl; o0.y = ctx[h][0][4 * g + 1] * invl;
        o0.z = ctx[h][0][4 * g + 2] * invl; o0.w = ctx[h][0][4 * g + 3] * invl;
        *(float4*)&orow[8 * g + 4 * hi] = o0;
        o1.x = ctx[h][1][4 * g + 0] * invl; o1.y = ctx[h][1][4 * g + 1] * invl;
        o1.z = ctx[h][1][4 * g + 2] * invl; o1.w = ctx[h][1][4 * g + 3] * invl;
        *(float4*)&orow[32 + 8 * g + 4 * hi] = o1;
      }
    }
  } else {
#pragma unroll
    for (int h = 0; h < 2; ++h){
      size_t row = (size_t)ksplit * 65536 + slice * 4096 + q0 + h * 32 + q;
      float* prow = pctx + row * 64;
#pragma unroll
      for (int g = 0; g < 4; ++g){
        float4 o0, o1;
        o0.x = ctx[h][0][4 * g + 0]; o0.y = ctx[h][0][4 * g + 1];
        o0.z = ctx[h][0][4 * g + 2]; o0.w = ctx[h][0][4 * g + 3];
        *(float4*)&prow[8 * g + 4 * hi] = o0;
        o1.x = ctx[h][1][4 * g + 0]; o1.y = ctx[h][1][4 * g + 1];
        o1.z = ctx[h][1][4 * g + 2]; o1.w = ctx[h][1][4 * g + 3];
        *(float4*)&prow[32 + 8 * g + 4 * hi] = o1;
      }
      if (hi == 0){
        f32x2 mlv = {m_run[h], lacc[h][0]};
        *(f32x2*)&pml[row * 2] = mlv;
      }
    }
  }
}

// ---------------- split-K merge (m in natural-log domain) ----------------
__global__ __launch_bounds__(256) void k_merge(const float* __restrict__ pctx, const float* __restrict__ pml,
                                               float* __restrict__ out){
  int idx = blockIdx.x * 256 + threadIdx.x;   // 65536 rows * 16 quads
  int row = idx >> 4, dq = (idx & 15) * 4;
  f32x2 ml0 = *(const f32x2*)&pml[(size_t)row * 2];
  f32x2 ml1 = *(const f32x2*)&pml[((size_t)65536 + row) * 2];
  float ms = fmaxf(ml0[0], ml1[0]);
  float w0 = ex2((ml0[0] - ms) * LOG2E);
  float w1 = ex2((ml1[0] - ms) * LOG2E);
  float rdenom = 1.0f / (w0 * ml0[1] + w1 * ml1[1]);
  float4 c0 = *(const float4*)&pctx[(size_t)row * 64 + dq];
  float4 c1 = *(const float4*)&pctx[((size_t)65536 + row) * 64 + dq];
  float4 o;
  o.x = (w0 * c0.x + w1 * c1.x) * rdenom;
  o.y = (w0 * c0.y + w1 * c1.y) * rdenom;
  o.z = (w0 * c0.z + w1 * c1.z) * rdenom;
  o.w = (w0 * c0.w + w1 * c1.w) * rdenom;
  int slice = row >> 12, s = row & 4095;
  int b = slice >> 3, head = slice & 7;
  *(float4*)&out[(size_t)(b * 4096 + s) * 512 + head * 64 + dq] = o;
}

extern "C" void kernel_launch(void* const* d_in, const int* in_sizes, int n_in,
                              void* d_out, int out_size, void* d_ws, size_t ws_size,
                              hipStream_t stream) {
  const float* hidden = (const float*)d_in[0];
  const float* mask   = (const float*)d_in[1];
  const float* Wq = (const float*)d_in[2];
  const float* bq = (const float*)d_in[3];
  const float* Wk = (const float*)d_in[4];
  const float* bk = (const float*)d_in[5];
  const float* Wv = (const float*)d_in[6];
  const float* bv = (const float*)d_in[7];
  float* out = (float*)d_out;
  char* ws = (char*)d_ws;

  u16* hb    = (u16*)(ws + 0x00000000);   // 8192x512 bf16      (8 MiB)
  u16* wt    = (u16*)(ws + 0x00900000);   // 1536x512 bf16      (1.5 MiB)
  float* bc  = (float*)(ws + 0x00B00000); // 1536 f32
  float* cs  = (float*)(ws + 0x00B10000); // 4096x64x2 f32      (2 MiB)
  u16* qws   = (u16*)(ws + 0x00E00000);   // 16x4096x64 bf16    (8 MiB)
  u16* kws   = (u16*)(ws + 0x01600000);   // 16x4096x64 bf16
  u16* vtws  = (u16*)(ws + 0x01E00000);   // 16x64x4096 bf16
  float* pctx= (float*)(ws + 0x02600000); // 2x16 MiB
  float* pml = (float*)(ws + 0x04600000); // 2x0.5 MiB

  bool split = ws_size >= 0x04700000ull;

  k_prep<<<dim3(2752), dim3(256), 0, stream>>>(hidden, hb, cs, Wq, Wk, Wv, bq, bk, bv, wt, bc);
  k_proj<<<dim3(64, 12), dim3(256), 0, stream>>>(hb, wt, bc, cs, qws, kws, vtws);
  if (split){
    k_attn<2><<<dim3(512), dim3(256), 0, stream>>>(qws, kws, vtws, mask, out, pctx, pml);
    k_merge<<<dim3(4096), dim3(256), 0, stream>>>(pctx, pml, out);
  } else {
    k_attn<1><<<dim3(256), dim3(256), 0, stream>>>(qws, kws, vtws, mask, out, pctx, pml);
  }
}